// Round 1
// baseline (242.683 us; speedup 1.0000x reference)
//
#include <hip/hip_runtime.h>
#include <math.h>

#define NUM_VARS 64
#define KK       32
#define NUM_CATS 256
#define LL       4
#define EE       16384
#define NN       8192
#define CC       4
#define BB       1024
#define NUM_INPUT 2048           // NUM_VARS * KK
#define TOTAL_ROWS 34816         // NUM_INPUT + LL*NN
#define NP       8               // nodes per block in layer kernel
#define ROOT_CHUNKS 64           // row-chunks in root partial reduce

// ---------------------------------------------------------------------------
// Input layer: nm[v*K + k][b] = input_logp[v][k][inputs[b][v]]
// grid: (B/256, NUM_VARS), block: 256
// ---------------------------------------------------------------------------
__global__ void input_kernel(const int* __restrict__ inputs,
                             const float* __restrict__ input_logp,
                             float* __restrict__ nm) {
    int b = blockIdx.x * 256 + threadIdx.x;
    int v = blockIdx.y;
    int cat = inputs[b * NUM_VARS + v];
    const float* lp = input_logp + ((size_t)v * KK) * NUM_CATS + cat;
    float* dst = nm + (size_t)(v * KK) * BB + b;
#pragma unroll
    for (int k = 0; k < KK; ++k) {
        dst[(size_t)k * BB] = lp[(size_t)k * NUM_CATS];
    }
}

__device__ __forceinline__ float lse4(float a, float b, float c, float d) {
    float m = fmaxf(fmaxf(a, b), fmaxf(c, d));
    float s = __expf(a - m) + __expf(b - m) + __expf(c - m) + __expf(d - m);
    return m + __logf(s);
}

// ---------------------------------------------------------------------------
// One sum layer. Each thread handles 4 consecutive batch cols (float4);
// block of 256 threads covers all B=1024. grid.x = NN/NP.
// nm4: node_mars viewed as rows of 256 float4. out4: this layer's output rows.
// ---------------------------------------------------------------------------
__global__ void layer_kernel(const float4* __restrict__ nm4,
                             float4* __restrict__ out4,
                             const int2* __restrict__ prod,   // E pairs
                             const int4* __restrict__ sch,    // N x 4 child ids
                             const float4* __restrict__ slw)  // N x 4 log-weights
{
    int t = threadIdx.x;                 // 0..255 -> 4 batch cols each
    int n0 = blockIdx.x * NP;
    for (int i = 0; i < NP; ++i) {
        int n = n0 + i;
        int4 s = sch[n];
        float4 w = slw[n];
        int2 p0 = prod[s.x];
        int2 p1 = prod[s.y];
        int2 p2 = prod[s.z];
        int2 p3 = prod[s.w];

        float4 a0 = nm4[(size_t)p0.x * (BB / 4) + t];
        float4 b0 = nm4[(size_t)p0.y * (BB / 4) + t];
        float4 a1 = nm4[(size_t)p1.x * (BB / 4) + t];
        float4 b1 = nm4[(size_t)p1.y * (BB / 4) + t];
        float4 a2 = nm4[(size_t)p2.x * (BB / 4) + t];
        float4 b2 = nm4[(size_t)p2.y * (BB / 4) + t];
        float4 a3 = nm4[(size_t)p3.x * (BB / 4) + t];
        float4 b3 = nm4[(size_t)p3.y * (BB / 4) + t];

        float4 r;
        r.x = lse4(w.x + a0.x + b0.x, w.y + a1.x + b1.x,
                   w.z + a2.x + b2.x, w.w + a3.x + b3.x);
        r.y = lse4(w.x + a0.y + b0.y, w.y + a1.y + b1.y,
                   w.z + a2.y + b2.y, w.w + a3.y + b3.y);
        r.z = lse4(w.x + a0.z + b0.z, w.y + a1.z + b1.z,
                   w.z + a2.z + b2.z, w.w + a3.z + b3.z);
        r.w = lse4(w.x + a0.w + b0.w, w.y + a1.w + b1.w,
                   w.z + a2.w + b2.w, w.w + a3.w + b3.w);

        out4[(size_t)n * (BB / 4) + t] = r;
    }
}

// ---------------------------------------------------------------------------
// Root reduce, stage 1: each block (1024 threads = one thread per batch col)
// online-logsumexps 8192/ROOT_CHUNKS rows; writes partial (m, s).
// ---------------------------------------------------------------------------
__global__ void root_partial(const float* __restrict__ last,  // N x B
                             const float* __restrict__ rlw,   // N
                             float* __restrict__ pm,
                             float* __restrict__ ps) {
    int b = threadIdx.x;                       // 0..1023
    int chunk = blockIdx.x;                    // 0..ROOT_CHUNKS-1
    int rows = NN / ROOT_CHUNKS;               // 128
    int n0 = chunk * rows;
    float m = -INFINITY, s = 0.f;
    for (int i = 0; i < rows; ++i) {
        int n = n0 + i;
        float v = rlw[n] + last[(size_t)n * BB + b];
        float nm_ = fmaxf(m, v);
        s = s * __expf(m - nm_) + __expf(v - nm_);
        m = nm_;
    }
    pm[chunk * BB + b] = m;
    ps[chunk * BB + b] = s;
}

// ---------------------------------------------------------------------------
// Root reduce, stage 2: combine ROOT_CHUNKS partials per batch col.
// ---------------------------------------------------------------------------
__global__ void root_final(const float* __restrict__ pm,
                           const float* __restrict__ ps,
                           float* __restrict__ out) {
    int b = blockIdx.x * 256 + threadIdx.x;
    float m = -INFINITY;
#pragma unroll
    for (int c = 0; c < ROOT_CHUNKS; ++c) m = fmaxf(m, pm[c * BB + b]);
    float s = 0.f;
#pragma unroll
    for (int c = 0; c < ROOT_CHUNKS; ++c)
        s += ps[c * BB + b] * __expf(pm[c * BB + b] - m);
    out[b] = m + __logf(s);
}

extern "C" void kernel_launch(void* const* d_in, const int* in_sizes, int n_in,
                              void* d_out, int out_size, void* d_ws, size_t ws_size,
                              hipStream_t stream) {
    const int*   inputs      = (const int*)d_in[0];
    const float* input_logp  = (const float*)d_in[1];
    const int*   prod_ids    = (const int*)d_in[2];
    const int*   sum_ch_ids  = (const int*)d_in[3];
    const float* sum_logw    = (const float*)d_in[4];
    const float* root_logw   = (const float*)d_in[5];
    float* out = (float*)d_out;

    float* nm = (float*)d_ws;                          // [34816][1024]
    float* pm = nm + (size_t)TOTAL_ROWS * BB;          // [64][1024]
    float* ps = pm + (size_t)ROOT_CHUNKS * BB;         // [64][1024]

    input_kernel<<<dim3(BB / 256, NUM_VARS), 256, 0, stream>>>(inputs, input_logp, nm);

    for (int l = 0; l < LL; ++l) {
        const int*   prod = prod_ids   + (size_t)l * EE * 2;
        const int*   sch  = sum_ch_ids + (size_t)l * NN * CC;
        const float* slw  = sum_logw   + (size_t)l * NN * CC;
        float* outl = nm + (size_t)(NUM_INPUT + l * NN) * BB;
        layer_kernel<<<NN / NP, 256, 0, stream>>>(
            (const float4*)nm, (float4*)outl,
            (const int2*)prod, (const int4*)sch, (const float4*)slw);
    }

    const float* last = nm + (size_t)(NUM_INPUT + (LL - 1) * NN) * BB;
    root_partial<<<ROOT_CHUNKS, 1024, 0, stream>>>(last, root_logw, pm, ps);
    root_final<<<BB / 256, 256, 0, stream>>>(pm, ps, out);
}